// Round 12
// baseline (359.274 us; speedup 1.0000x reference)
//
#include <hip/hip_runtime.h>
#include <math.h>
#include <float.h>

// VQVAE forward, MI355X. Round 23: ADIRECT. R22 confirmed the regime gate:
// G1 at 697 TF == the guide's measured 2-phase structural ceiling (m233);
// counted-vmcnt/raw-barrier/B-dbuf all null because the stage->barrier->
// compute lockstep IS the critical path. Fix: remove the structure. We own
// every operand layout except x, so producers now write intermediates
// (h1, z, h3) in PACKED MFMA-fragment order; consumers (G2, G4, dist) read
// A-fragments as single coalesced 1KB global loads -- NO LDS staging, NO
// barriers in the K-loop, fully independent waves with 1-deep register
// prefetch. G1 (fp32 A) and G3 (indirect A) keep their LDS path, epilogues
// now emit packed layout. dist: Z+E packed-direct, LDS 32KB->3KB. rescore
// reads packed z. Same product set/order -> bit-identical numerics.

typedef __attribute__((ext_vector_type(8))) short short8;      // MFMA A/B frag
typedef __attribute__((ext_vector_type(4))) float floatx4;     // MFMA C/D frag
typedef __attribute__((ext_vector_type(4))) unsigned short ushort4v;
typedef __attribute__((ext_vector_type(8))) unsigned short ushort8v;

__device__ __forceinline__ unsigned short f2bf(float f) {
  union { float f; unsigned u; } v; v.f = f;
  unsigned u = v.u;
  return (unsigned short)((u + 0x7FFFu + ((u >> 16) & 1u)) >> 16);
}
__device__ __forceinline__ float bf2f(unsigned short s) {
  union { unsigned u; float f; } v; v.u = ((unsigned)s) << 16;
  return v.f;
}

__device__ __forceinline__ void glds16(const void* g, void* l) {
  __builtin_amdgcn_global_load_lds(
      (const __attribute__((address_space(1))) unsigned int*)g,
      (__attribute__((address_space(3))) unsigned int*)l, 16, 0, 0);
}

template <int N> __device__ __forceinline__ void vmwait() {
  if constexpr (N == 0)       asm volatile("s_waitcnt vmcnt(0)" ::: "memory");
  else if constexpr (N == 5)  asm volatile("s_waitcnt vmcnt(5)" ::: "memory");
  else if constexpr (N == 6)  asm volatile("s_waitcnt vmcnt(6)" ::: "memory");
  else if constexpr (N == 8)  asm volatile("s_waitcnt vmcnt(8)" ::: "memory");
  else if constexpr (N == 12) asm volatile("s_waitcnt vmcnt(12)" ::: "memory");
  else static_assert(N == 0, "add vmcnt literal");
}
__device__ __forceinline__ void lgkm0() {
  asm volatile("s_waitcnt lgkmcnt(0)" ::: "memory");
}

// bank-swizzle: 16B-chunk XOR within a row; uses row bits 0-3 only.
__device__ __forceinline__ int fswz(int r) { return (r ^ (r >> 2)) & 3; }

__device__ __forceinline__ unsigned packkey(float d, int c) {
  unsigned b = __float_as_uint(d);
  b = (b & 0x80000000u) ? ~b : (b | 0x80000000u);
  return (b & 0xFFFFF800u) | (unsigned)c;
}
__device__ __forceinline__ void ins3(unsigned k, unsigned& v1, unsigned& v2,
                                     unsigned& v3) {
  unsigned t1 = min(v1, k), c1 = max(v1, k);
  unsigned t2 = min(v2, c1), c2 = max(v2, c1);
  v1 = t1; v2 = t2; v3 = min(v3, c2);
}

// fp32 -> packed-fragment-order hi/mid. Element (r,c) of a [Rp][Cp] padded
// matrix lands at tile (r>>4, c>>5), lane (r&15)|(((c>>3)&3)<<4), j c&7.
template <int Cp>
__device__ __forceinline__ void conv_pack(
    const float* __restrict__ src, unsigned short* __restrict__ ph,
    unsigned short* __restrict__ pm, int R, int C, int b) {
  const int t = b * 256 + (int)threadIdx.x;
  const int r = t / Cp, c = t & (Cp - 1);
  float v = (r < R && c < C) ? src[(long)r * C + c] : 0.f;
  unsigned short h = f2bf(v);
  unsigned short m = f2bf(v - bf2f(h));
  const long dst = ((long)(r >> 4) * (Cp >> 5) + (c >> 5)) * 512 +
                   (((r & 15) | (((c >> 3) & 3) << 4)) << 3) + (c & 7);
  ph[dst] = h; pm[dst] = m;
}

// fused prep: regions (block counts): W1 2048 | W2 512 | W3 512 | W4 2048 |
// emb 2048 (linear + packed) | enorm 512. Grid = 7680 blocks.
__global__ __launch_bounds__(256) void prep(
    const float* __restrict__ W1, unsigned short* __restrict__ w1ph, unsigned short* __restrict__ w1pm,
    const float* __restrict__ W2, unsigned short* __restrict__ w2ph, unsigned short* __restrict__ w2pm,
    const float* __restrict__ W3, unsigned short* __restrict__ w3ph, unsigned short* __restrict__ w3pm,
    const float* __restrict__ W4, unsigned short* __restrict__ w4ph, unsigned short* __restrict__ w4pm,
    const float* __restrict__ emb, unsigned short* __restrict__ eh, unsigned short* __restrict__ em,
    unsigned short* __restrict__ eph, unsigned short* __restrict__ epm,
    float* __restrict__ enorm) {
  int b = blockIdx.x;
  if (b < 2048) {                       // W1: 400x1024 -> 512x1024 packed
    conv_pack<1024>(W1, w1ph, w1pm, 400, 1024, b);
  } else if (b < 2560) {                // W2: 256x400 -> 256x512 packed
    conv_pack<512>(W2, w2ph, w2pm, 256, 400, b - 2048);
  } else if (b < 3072) {                // W3: 400x256 -> 512x256 packed
    conv_pack<256>(W3, w3ph, w3pm, 400, 256, b - 2560);
  } else if (b < 5120) {                // W4: 1024x400 -> 1024x512 packed
    conv_pack<512>(W4, w4ph, w4pm, 1024, 400, b - 3072);
  } else if (b < 7168) {                // emb: linear eh/em + packed eph/epm
    const int t = (b - 5120) * 256 + (int)threadIdx.x;
    const int r = t >> 8, c = t & 255;
    float v = emb[(long)r * 256 + c];
    unsigned short h = f2bf(v);
    unsigned short m = f2bf(v - bf2f(h));
    eh[t] = h; em[t] = m;
    const long dst = ((long)(r >> 4) * 8 + (c >> 5)) * 512 +
                     (((r & 15) | (((c >> 3) & 3) << 4)) << 3) + (c & 7);
    eph[dst] = h; epm[dst] = m;
  } else {                              // enorm: 4 rows/block, 1 wave/row
    const int gtid = (b - 7168) * 256 + (int)threadIdx.x;
    const int j = gtid >> 6;
    const int lane = threadIdx.x & 63;
    float4 v = *(const float4*)(emb + (long)j * 256 + (lane << 2));
    float s = v.x * v.x + v.y * v.y + v.z * v.z + v.w * v.w;
#pragma unroll
    for (int off = 1; off < 64; off <<= 1) s += __shfl_xor(s, off, 64);
    if (lane == 0) enorm[j] = s;
  }
}

#define BK 32

enum { EPI_NONE = 0, EPI_RELU = 1, EPI_SIGMOID = 2 };
// OMODE: 0 = fp32 out, 1 = PACKED hi/mid out, 3 = PACKED hi-only out
// NPROD: 3 = ah*bh + ah*bm + am*bh (fp32-grade); 2 = ah*bh + ah*bm (A hi-only)
// ADIRECT: A read from PACKED global (fragment order), no LDS, no K-loop
// barriers, 1-deep register prefetch. Otherwise A staged in LDS as before.
// Wave grid WM x WN; wave tile (TMW*16) x (TNW*16).
// Grid: blockIdx.x = row-block (XCD-affine), blockIdx.y = col-block.

template <int EPI, bool INDIRECT, bool ASPLIT, bool ADIRECT, int OMODE,
          int TMW, int TNW, int WM, int WN, int NPROD, int MINW>
__global__ __launch_bounds__(WM * WN * 64, MINW) void mfma_gemm(
    const float* __restrict__ Af, const unsigned short* __restrict__ Ahg,
    const unsigned short* __restrict__ Amg, const unsigned short* __restrict__ Bph,
    const unsigned short* __restrict__ Bpm, const float* __restrict__ bias,
    float* __restrict__ Cf, unsigned short* __restrict__ Ohi,
    unsigned short* __restrict__ Omid, const int* __restrict__ aidx,
    int M, int N, int K, int Nreal) {
  constexpr int WAVES = WM * WN;
  constexpr int THREADS = WAVES * 64;
  constexpr int BM = WM * TMW * 16;
  constexpr int BN = WN * TNW * 16;
  constexpr int NSA = BM / 16;            // A 16-row staging slots
  constexpr int ASW = (NSA + WAVES - 1) / WAVES;
  constexpr int ACELL = (BM * BK) / (4 * THREADS);  // fp32-A staging cells
  constexpr int RPC = THREADS / 8;        // rows per fp32 staging cell
  constexpr int B_CNT = TNW * 2;                         // B loads / K-step
  constexpr int G_CNT = ASW * ((NPROD == 3) ? 2 : 1);    // glds / K-step
  constexpr int NWAIT = B_CNT + G_CNT;    // steady-state vmcnt (LDS path)

  constexpr int A_SH  = BM * BK;                                   // shorts
  constexpr int AM_SH = (NPROD == 3 || !ASPLIT) ? BM * BK : 0;     // shorts
  constexpr int STAGE_SH = ADIRECT ? 0 : (A_SH + AM_SH);           // one phase
  constexpr int OUT_SH = (OMODE == 0) ? 0 : BM * (BN + 8);
  constexpr int SMEM_RAW = (2 * STAGE_SH > OUT_SH) ? 2 * STAGE_SH : OUT_SH;
  constexpr int SMEM_SH = (SMEM_RAW > 0) ? SMEM_RAW : 8;
  __shared__ __align__(16) unsigned short smem[SMEM_SH];
  unsigned short (*OutS)[BN + 8] = (unsigned short(*)[BN + 8])smem;

  const int tid = threadIdx.x, lane = tid & 63, wave = tid >> 6;
  const int wm = wave / WN, wn = wave % WN;
  const int row0 = blockIdx.x * BM, col0 = blockIdx.y * BN;
  const int kswz = (((lane & 3) ^ fswz(lane >> 2)) * 8);
  const int KC = K >> 5;

  // B packed fragment base pointers: one coalesced 1KB load per frag.
  const unsigned short *bPh[TNW], *bPm[TNW];
#pragma unroll
  for (int tn = 0; tn < TNW; tn++) {
    const int ct = (col0 >> 4) + wn * TNW + tn;
    const long o = (long)ct * KC * 512 + lane * 8;
    bPh[tn] = Bph + o;
    bPm[tn] = Bpm + o;
  }

  floatx4 acc[TMW][TNW];
#pragma unroll
  for (int i = 0; i < TMW; i++)
#pragma unroll
    for (int j = 0; j < TNW; j++) acc[i][j] = (floatx4)0.f;

  if constexpr (ADIRECT) {
    // ---- barrier-free K-loop: A and B packed-direct, 1-deep reg prefetch.
    const unsigned short *aPh[TMW], *aPm[TMW];
#pragma unroll
    for (int tm = 0; tm < TMW; tm++) {
      const long rt = (row0 >> 4) + wm * TMW + tm;
      aPh[tm] = Ahg + rt * KC * 512 + lane * 8;
      if (NPROD == 3) aPm[tm] = Amg + rt * KC * 512 + lane * 8;
    }
    short8 ach[TMW], acm[TMW], bch[TNW], bcm[TNW];
#pragma unroll
    for (int tm = 0; tm < TMW; tm++) {
      ach[tm] = *(const short8*)(aPh[tm]);
      if (NPROD == 3) acm[tm] = *(const short8*)(aPm[tm]);
    }
#pragma unroll
    for (int tn = 0; tn < TNW; tn++) {
      bch[tn] = *(const short8*)(bPh[tn]);
      bcm[tn] = *(const short8*)(bPm[tn]);
    }
    for (int kc = 0; kc < KC; kc++) {
      const bool more = (kc + 1) < KC;
      short8 anh[TMW], anm[TMW], bnh[TNW], bnm[TNW];
      if (more) {
        const int fo = (kc + 1) * 512;
#pragma unroll
        for (int tm = 0; tm < TMW; tm++) {
          anh[tm] = *(const short8*)(aPh[tm] + fo);
          if (NPROD == 3) anm[tm] = *(const short8*)(aPm[tm] + fo);
        }
#pragma unroll
        for (int tn = 0; tn < TNW; tn++) {
          bnh[tn] = *(const short8*)(bPh[tn] + fo);
          bnm[tn] = *(const short8*)(bPm[tn] + fo);
        }
      }
#pragma unroll
      for (int tn = 0; tn < TNW; tn++) {
#pragma unroll
        for (int tm = 0; tm < TMW; tm++) {
          acc[tm][tn] = __builtin_amdgcn_mfma_f32_16x16x32_bf16(ach[tm], bch[tn], acc[tm][tn], 0, 0, 0);
          acc[tm][tn] = __builtin_amdgcn_mfma_f32_16x16x32_bf16(ach[tm], bcm[tn], acc[tm][tn], 0, 0, 0);
          if (NPROD == 3)
            acc[tm][tn] = __builtin_amdgcn_mfma_f32_16x16x32_bf16(acm[tm], bch[tn], acc[tm][tn], 0, 0, 0);
        }
      }
      if (more) {
#pragma unroll
        for (int tm = 0; tm < TMW; tm++) {
          ach[tm] = anh[tm];
          if (NPROD == 3) acm[tm] = anm[tm];
        }
#pragma unroll
        for (int tn = 0; tn < TNW; tn++) { bch[tn] = bnh[tn]; bcm[tn] = bnm[tn]; }
      }
    }
  } else {
    // ---- LDS-staged A path (G1 fp32-convert / G3 indirect), counted barriers
    const unsigned short *aH[ASW], *aM2[ASW];
    const float* aF[(ACELL > 0) ? ACELL : 1];
    if (ASPLIT) {
#pragma unroll
      for (int j = 0; j < ASW; j++) {
        const int slot = wave + j * WAVES;
        if (slot < NSA) {
          const int rl = slot * 16 + (lane >> 2);
          const long ar = INDIRECT ? (long)aidx[row0 + rl] : (long)(row0 + rl);
          aH[j] = Ahg + ar * K + kswz;
          if (NPROD == 3) aM2[j] = Amg + ar * K + kswz;
        }
      }
    } else {
#pragma unroll
      for (int i = 0; i < ACELL; i++)
        aF[i] = Af + (long)(row0 + i * RPC + (tid >> 3)) * K + (tid & 7) * 4;
    }
    auto stage_glds = [&](int p, int k0) {
      unsigned short* b = smem + p * STAGE_SH;
      if (ASPLIT) {
#pragma unroll
        for (int j = 0; j < ASW; j++) {
          const int slot = wave + j * WAVES;
          if (slot < NSA) {
            glds16(aH[j] + k0, b + slot * 512);
            if (NPROD == 3) glds16(aM2[j] + k0, b + A_SH + slot * 512);
          }
        }
      }
    };
    auto stage_awrite = [&](int p, const float4* areg) {
      unsigned short* b = smem + p * STAGE_SH;
#pragma unroll
      for (int i = 0; i < ACELL; i++) {
        const int r = i * RPC + (tid >> 3);
        const int c16 = (tid & 7) >> 1, lo = tid & 1;
        const int q4 = (((c16 ^ fswz(r)) << 1) | lo) * 4;
        ushort4v h, m;
        h.x = f2bf(areg[i].x); m.x = f2bf(areg[i].x - bf2f(h.x));
        h.y = f2bf(areg[i].y); m.y = f2bf(areg[i].y - bf2f(h.y));
        h.z = f2bf(areg[i].z); m.z = f2bf(areg[i].z - bf2f(h.z));
        h.w = f2bf(areg[i].w); m.w = f2bf(areg[i].w - bf2f(h.w));
        *(ushort4v*)(b + r * BK + q4) = h;
        *(ushort4v*)(b + A_SH + r * BK + q4) = m;
      }
    };

    if (!ASPLIT) {
      float4 a0[(ACELL > 0) ? ACELL : 1];
#pragma unroll
      for (int i = 0; i < ACELL; i++) a0[i] = *(const float4*)(aF[i]);
      stage_awrite(0, a0);
    }
    stage_glds(0, 0);
    short8 bch[TNW], bcm[TNW];
#pragma unroll
    for (int tn = 0; tn < TNW; tn++) {
      bch[tn] = *(const short8*)(bPh[tn]);
      bcm[tn] = *(const short8*)(bPm[tn]);
    }
    __syncthreads();

    int p = 0;
    for (int k0 = 0; k0 < K; k0 += BK) {
      const bool more = (k0 + BK) < K;
      short8 bnh[TNW], bnm[TNW];
      float4 an[(ACELL > 0) ? ACELL : 1];
      if (more) {
        const int fo = ((k0 + BK) >> 5) * 512;
#pragma unroll
        for (int tn = 0; tn < TNW; tn++) {
          bnh[tn] = *(const short8*)(bPh[tn] + fo);
          bnm[tn] = *(const short8*)(bPm[tn] + fo);
        }
        if (!ASPLIT) {
#pragma unroll
          for (int i = 0; i < ACELL; i++) an[i] = *(const float4*)(aF[i] + k0 + BK);
        }
        stage_glds(p ^ 1, k0 + BK);
      }
      if (ASPLIT) {
        if (more) vmwait<NWAIT>(); else vmwait<0>();
      } else {
        lgkm0();
      }
      __builtin_amdgcn_s_barrier();
      __builtin_amdgcn_sched_barrier(0);
      {
        const unsigned short* b = smem + p * STAGE_SH;
        short8 ah[TMW], am[TMW];
#pragma unroll
        for (int tm = 0; tm < TMW; tm++) {
          const int rr = wm * (TMW * 16) + tm * 16 + (lane & 15);
          const int kk = (((lane >> 4) ^ fswz(rr)) * 8);
          ah[tm] = *(const short8*)(b + rr * BK + kk);
          if (NPROD == 3) am[tm] = *(const short8*)(b + A_SH + rr * BK + kk);
        }
#pragma unroll
        for (int tn = 0; tn < TNW; tn++) {
#pragma unroll
          for (int tm = 0; tm < TMW; tm++) {
            acc[tm][tn] = __builtin_amdgcn_mfma_f32_16x16x32_bf16(ah[tm], bch[tn], acc[tm][tn], 0, 0, 0);
            acc[tm][tn] = __builtin_amdgcn_mfma_f32_16x16x32_bf16(ah[tm], bcm[tn], acc[tm][tn], 0, 0, 0);
            if (NPROD == 3)
              acc[tm][tn] = __builtin_amdgcn_mfma_f32_16x16x32_bf16(am[tm], bch[tn], acc[tm][tn], 0, 0, 0);
          }
        }
      }
      if (more) {
        if (!ASPLIT) stage_awrite(p ^ 1, an);
#pragma unroll
        for (int tn = 0; tn < TNW; tn++) { bch[tn] = bnh[tn]; bcm[tn] = bnm[tn]; }
      }
      p ^= 1;
    }
  }

  // C/D layout: col = lane&15, row = (lane>>4)*4 + reg
  const int qd = lane >> 4, ln = lane & 15;
  if (OMODE == 0) {
#pragma unroll
    for (int tn = 0; tn < TNW; tn++) {
      const int c = col0 + wn * (TNW * 16) + tn * 16 + ln;
      const float bb = (c < Nreal) ? bias[c] : 0.f;
#pragma unroll
      for (int tm = 0; tm < TMW; tm++) {
#pragma unroll
        for (int reg = 0; reg < 4; reg++) {
          const int r = row0 + wm * (TMW * 16) + tm * 16 + qd * 4 + reg;
          float v = acc[tm][tn][reg] + bb;
          if (EPI == EPI_RELU) v = fmaxf(v, 0.f);
          if (EPI == EPI_SIGMOID) v = 1.f / (1.f + __expf(-v));
          Cf[(long)r * N + c] = v;
        }
      }
    }
  } else {
    // PACKED bf16 epilogue: OutS staging -> 1KB-per-wave tile stores.
    __syncthreads();  // staged-path aliasing + cross-wave OutS use
    float bbv[TNW];
#pragma unroll
    for (int tn = 0; tn < TNW; tn++) {
      const int c = col0 + wn * (TNW * 16) + tn * 16 + ln;
      bbv[tn] = (c < Nreal) ? bias[c] : 0.f;
    }
    constexpr int CTB = BN / 32;            // col subtiles per block
    constexpr int NSUB = (BM / 16) * CTB;   // 16x32 subtiles per block
    constexpr int ITS = NSUB / WAVES;
    const int KCo = N >> 5;
    // pass 1: hi
#pragma unroll
    for (int tn = 0; tn < TNW; tn++) {
      const int cl = wn * (TNW * 16) + tn * 16 + ln;
#pragma unroll
      for (int tm = 0; tm < TMW; tm++) {
#pragma unroll
        for (int reg = 0; reg < 4; reg++) {
          const int rl = wm * (TMW * 16) + tm * 16 + qd * 4 + reg;
          float v = acc[tm][tn][reg] + bbv[tn];
          if (EPI == EPI_RELU) v = fmaxf(v, 0.f);
          if (EPI == EPI_SIGMOID) v = 1.f / (1.f + __expf(-v));
          OutS[rl][cl] = f2bf(v);
        }
      }
    }
    __syncthreads();
#pragma unroll
    for (int i2 = 0; i2 < ITS; i2++) {
      const int s = i2 * WAVES + wave;
      const int rt = s / CTB, ct = s % CTB;
      ushort8v val = *(const ushort8v*)&OutS[rt * 16 + (lane & 15)][ct * 32 + (lane >> 4) * 8];
      const long tile = (long)((row0 >> 4) + rt) * KCo + ((col0 >> 5) + ct);
      *(ushort8v*)(Ohi + tile * 512 + lane * 8) = val;
    }
    if (OMODE == 1) {
      __syncthreads();
      // pass 2: mid
#pragma unroll
      for (int tn = 0; tn < TNW; tn++) {
        const int cl = wn * (TNW * 16) + tn * 16 + ln;
#pragma unroll
        for (int tm = 0; tm < TMW; tm++) {
#pragma unroll
          for (int reg = 0; reg < 4; reg++) {
            const int rl = wm * (TMW * 16) + tm * 16 + qd * 4 + reg;
            float v = acc[tm][tn][reg] + bbv[tn];
            if (EPI == EPI_RELU) v = fmaxf(v, 0.f);
            if (EPI == EPI_SIGMOID) v = 1.f / (1.f + __expf(-v));
            unsigned short h = f2bf(v);
            OutS[rl][cl] = f2bf(v - bf2f(h));
          }
        }
      }
      __syncthreads();
#pragma unroll
      for (int i2 = 0; i2 < ITS; i2++) {
        const int s = i2 * WAVES + wave;
        const int rt = s / CTB, ct = s % CTB;
        ushort8v val = *(const ushort8v*)&OutS[rt * 16 + (lane & 15)][ct * 32 + (lane >> 4) * 8];
        const long tile = (long)((row0 >> 4) + rt) * KCo + ((col0 >> 5) + ct);
        *(ushort8v*)(Omid + tile * 512 + lane * 8) = val;
      }
    }
  }
}

// dist candidates: grid (M/128 rows, 4 groups). Z and E both PACKED-direct
// from global: no LDS staging, no K-loop barriers, independent waves. LDS =
// 3KB reduce scratch only. Branchless packed-key top-3, one cross-lane merge.
__global__ __launch_bounds__(256, 2) void dist_topk(
    const unsigned short* __restrict__ Zph, const unsigned short* __restrict__ Zpm,
    const unsigned short* __restrict__ Eph, const unsigned short* __restrict__ Epm,
    const float* __restrict__ enorm, int* __restrict__ pidx, int M) {
  __shared__ unsigned rs[3 * 256];   // [3][2][128] reduce scratch

  const int tid = threadIdx.x, lane = tid & 63, wave = tid >> 6;
  const int wm = wave >> 1, wn = wave & 1;
  const int row0 = blockIdx.x * 128;
  const int col_base = blockIdx.y * 512;

  // packed A (z) fragment bases: KC = 8
  const unsigned short *aPh[4], *aPm[4];
#pragma unroll
  for (int tm = 0; tm < 4; tm++) {
    const long rt = (row0 >> 4) + wm * 4 + tm;
    aPh[tm] = Zph + rt * 8 * 512 + lane * 8;
    aPm[tm] = Zpm + rt * 8 * 512 + lane * 8;
  }

  unsigned k1[16], k2[16], k3[16];
#pragma unroll
  for (int s = 0; s < 16; s++) { k1[s] = 0xFFFFFFFFu; k2[s] = 0xFFFFFFFFu; k3[s] = 0xFFFFFFFFu; }

  floatx4 acc[4][4];
  for (int it = 0; it < 32; it++) {
    const int ch = it >> 3, kc = it & 7;
    if (kc == 0) {
#pragma unroll
      for (int i = 0; i < 4; i++)
#pragma unroll
        for (int j = 0; j < 4; j++) acc[i][j] = (floatx4)0.f;
    }
    short8 ah[4], am[4], bh[4], bm[4];
#pragma unroll
    for (int tm = 0; tm < 4; tm++) {
      ah[tm] = *(const short8*)(aPh[tm] + kc * 512);
      am[tm] = *(const short8*)(aPm[tm] + kc * 512);
    }
#pragma unroll
    for (int tn = 0; tn < 4; tn++) {
      const long fo = ((long)((col_base >> 4) + ch * 8 + wn * 4 + tn) * 8 + kc) * 512 + lane * 8;
      bh[tn] = *(const short8*)(Eph + fo);
      bm[tn] = *(const short8*)(Epm + fo);
    }
#pragma unroll
    for (int tn = 0; tn < 4; tn++) {
#pragma unroll
      for (int tm = 0; tm < 4; tm++) {
        acc[tm][tn] = __builtin_amdgcn_mfma_f32_16x16x32_bf16(ah[tm], bh[tn], acc[tm][tn], 0, 0, 0);
        acc[tm][tn] = __builtin_amdgcn_mfma_f32_16x16x32_bf16(ah[tm], bm[tn], acc[tm][tn], 0, 0, 0);
        acc[tm][tn] = __builtin_amdgcn_mfma_f32_16x16x32_bf16(am[tm], bh[tn], acc[tm][tn], 0, 0, 0);
      }
    }
    if (kc == 7) {  // chunk epilogue: fold into top-3
      const int c0 = col_base + ch * 128;
#pragma unroll
      for (int tn = 0; tn < 4; tn++) {
        const int c = c0 + wn * 64 + tn * 16 + (lane & 15);
        const float en = enorm[c];
#pragma unroll
        for (int tm = 0; tm < 4; tm++)
#pragma unroll
          for (int reg = 0; reg < 4; reg++) {
            float d = en - 2.f * acc[tm][tn][reg];
            ins3(packkey(d, c), k1[tm * 4 + reg], k2[tm * 4 + reg], k3[tm * 4 + reg]);
          }
      }
    }
  }

#pragma unroll
  for (int s = 0; s < 16; s++) {
#pragma unroll
    for (int off = 1; off < 16; off <<= 1) {
      unsigned o1 = __shfl_xor(k1[s], off, 64);
      unsigned o2 = __shfl_xor(k2[s], off, 64);
      unsigned o3 = __shfl_xor(k3[s], off, 64);
      ins3(o1, k1[s], k2[s], k3[s]);
      ins3(o2, k1[s], k2[s], k3[s]);
      ins3(o3, k1[s], k2[s], k3[s]);
    }
  }
  if ((lane & 15) == 0) {
#pragma unroll
    for (int s = 0; s < 16; s++) {
      int rl = wm * 64 + (s >> 2) * 16 + (lane >> 4) * 4 + (s & 3);
      rs[0 + wn * 128 + rl] = k1[s];
      rs[256 + wn * 128 + rl] = k2[s];
      rs[512 + wn * 128 + rl] = k3[s];
    }
  }
  __syncthreads();
  if (tid < 128) {
    unsigned v1 = rs[0 + tid], v2 = rs[256 + tid], v3 = rs[512 + tid];
    ins3(rs[0 + 128 + tid], v1, v2, v3);
    ins3(rs[256 + 128 + tid], v1, v2, v3);
    ins3(rs[512 + 128 + tid], v1, v2, v3);
    const long base = ((long)blockIdx.y * M + (row0 + tid)) * 4;
    pidx[base + 0] = (int)(v1 & 0x7FFu);
    pidx[base + 1] = (int)(v2 & 0x7FFu);
    pidx[base + 2] = (int)(v3 & 0x7FFu);
  }
}

// exact fp32 rescore of 12 candidates/row; z = hi + mid read from PACKED
// layout (bit-identical to what dist scored). One wave per row.
__global__ __launch_bounds__(256) void rescore(
    const unsigned short* __restrict__ zph, const unsigned short* __restrict__ zpm,
    const float* __restrict__ emb, const float* __restrict__ enorm,
    const int* __restrict__ pidx, int* __restrict__ idx, int M) {
  const int wave = threadIdx.x >> 6, lane = threadIdx.x & 63;
  const int r = blockIdx.x * 4 + wave;
  // packed addr of z[r][lane*4 .. +3]
  const long po = ((long)(r >> 4) * 8 + (lane >> 3)) * 512 +
                  (((r & 15) | (((lane >> 1) & 3) << 4)) << 3) + (lane & 1) * 4;
  ushort4v hz = *(const ushort4v*)(zph + po);
  ushort4v mz = *(const ushort4v*)(zpm + po);
  float4 zv;
  zv.x = bf2f(hz.x) + bf2f(mz.x);
  zv.y = bf2f(hz.y) + bf2f(mz.y);
  zv.z = bf2f(hz.z) + bf2f(mz.z);
  zv.w = bf2f(hz.w) + bf2f(mz.w);
  float best = FLT_MAX;
  int bi = 0x7fffffff;
  for (int g = 0; g < 4; g++) {
#pragma unroll
    for (int s = 0; s < 3; s++) {
      const int j = pidx[((long)g * M + r) * 4 + s];
      float4 ev = *(const float4*)(emb + (long)j * 256 + lane * 4);
      float t = zv.x * ev.x + zv.y * ev.y + zv.z * ev.z + zv.w * ev.w;
#pragma unroll
      for (int off = 1; off < 64; off <<= 1) t += __shfl_xor(t, off, 64);
      const float d = enorm[j] - 2.f * t;
      if (d < best || (d == best && j < bi)) { best = d; bi = j; }
    }
  }
  if (lane == 0) idx[r] = bi;
}

extern "C" void kernel_launch(void* const* d_in, const int* in_sizes, int n_in,
                              void* d_out, int out_size, void* d_ws, size_t ws_size,
                              hipStream_t stream) {
  const float* x   = (const float*)d_in[0];
  const float* W1  = (const float*)d_in[1];
  const float* b1  = (const float*)d_in[2];
  const float* W2  = (const float*)d_in[3];
  const float* b2  = (const float*)d_in[4];
  const float* W3  = (const float*)d_in[5];
  const float* b3  = (const float*)d_in[6];
  const float* W4  = (const float*)d_in[7];
  const float* b4  = (const float*)d_in[8];
  const float* emb = (const float*)d_in[9];
  float* out = (float*)d_out;

  const int BZ = 16384, IN = 1024, H = 400, Hp = 512, D = 256;

  char* ws = (char*)d_ws;
  size_t off = 0;
  auto alloc = [&](size_t bytes) {
    void* p = ws + off;
    off += (bytes + 255) & ~(size_t)255;
    return p;
  };
  unsigned short* w1ph = (unsigned short*)alloc((size_t)Hp * IN * 2);
  unsigned short* w1pm = (unsigned short*)alloc((size_t)Hp * IN * 2);
  unsigned short* w2ph = (unsigned short*)alloc((size_t)D * Hp * 2);
  unsigned short* w2pm = (unsigned short*)alloc((size_t)D * Hp * 2);
  unsigned short* w3ph = (unsigned short*)alloc((size_t)Hp * D * 2);
  unsigned short* w3pm = (unsigned short*)alloc((size_t)Hp * D * 2);
  unsigned short* w4ph = (unsigned short*)alloc((size_t)IN * Hp * 2);
  unsigned short* w4pm = (unsigned short*)alloc((size_t)IN * Hp * 2);
  unsigned short* eh  = (unsigned short*)alloc((size_t)2048 * D * 2);
  unsigned short* em  = (unsigned short*)alloc((size_t)2048 * D * 2);
  unsigned short* eph = (unsigned short*)alloc((size_t)2048 * D * 2);
  unsigned short* epm = (unsigned short*)alloc((size_t)2048 * D * 2);
  float* enorm = (float*)alloc((size_t)2048 * 4);
  unsigned short* h1ph = (unsigned short*)alloc((size_t)BZ * Hp * 2);  // 16MB
  unsigned short* h1pm = (unsigned short*)alloc((size_t)BZ * Hp * 2);  // 16MB
  unsigned short* zph  = (unsigned short*)alloc((size_t)BZ * D * 2);   // 8MB
  unsigned short* zpm  = (unsigned short*)alloc((size_t)BZ * D * 2);   // 8MB
  // aliases (lifetimes disjoint on the sequential stream):
  int* pidx = (int*)h1ph;                      // h1 dead after GEMM2 (1MB used)
  int* idx  = ((int*)h1ph) + (size_t)4 * BZ * 4;
  unsigned short* h3ph = h1pm;                 // h1pm dead after GEMM2 (16MB)

  // fused prep: packed weight/codebook conversions + emb norms, one dispatch
  prep<<<dim3(7680), dim3(256), 0, stream>>>(
      W1, w1ph, w1pm, W2, w2ph, w2pm, W3, w3ph, w3pm, W4, w4ph, w4pm,
      emb, eh, em, eph, epm, enorm);

  // h1 = relu(x @ W1^T + b1) -> PACKED hi/mid  (bf16x3, 128x128, 8 waves)
  mfma_gemm<EPI_RELU, false, false, false, 1, 4, 2, 2, 4, 3, 4>
      <<<dim3(BZ / 128, Hp / 128), dim3(512), 0, stream>>>(
      x, nullptr, nullptr, w1ph, w1pm, b1, nullptr, h1ph, h1pm, nullptr, BZ, Hp, IN, H);
  // z = h1 @ W2^T + b2 -> PACKED hi/mid  (ADIRECT bf16x3, 64x64, 4 waves)
  mfma_gemm<EPI_NONE, false, false, true, 1, 2, 2, 2, 2, 3, 2>
      <<<dim3(BZ / 64, D / 64), dim3(256), 0, stream>>>(
      nullptr, h1ph, h1pm, w2ph, w2pm, b2, nullptr, zph, zpm, nullptr, BZ, D, Hp, D);
  // dist candidates: top-3 per 512-col group (XCD-affine grid), bf16x3
  dist_topk<<<dim3(BZ / 128, 4), dim3(256), 0, stream>>>(zph, zpm, eph, epm, enorm, pidx, BZ);
  // exact fp32 rescore of 12 -> idx
  rescore<<<dim3(BZ / 4), dim3(256), 0, stream>>>(zph, zpm, emb, enorm, pidx, idx, BZ);
  // h3 = relu(emb[idx] @ W3^T + b3) -> PACKED hi  (bf16x2, 128x128, 8 waves)
  mfma_gemm<EPI_RELU, true, true, false, 3, 4, 2, 2, 4, 2, 4>
      <<<dim3(BZ / 128, Hp / 128), dim3(512), 0, stream>>>(
      nullptr, eh, nullptr, w3ph, w3pm, b3, nullptr, h3ph, nullptr, idx, BZ, Hp, D, H);
  // out = sigmoid(h3 @ W4^T + b4) -> fp32 (ADIRECT bf16x2, 128x64, 4 waves)
  mfma_gemm<EPI_SIGMOID, false, false, true, 0, 4, 2, 2, 2, 2, 2>
      <<<dim3(BZ / 128, IN / 64), dim3(256), 0, stream>>>(
      nullptr, h3ph, nullptr, w4ph, w4pm, b4, out, nullptr, nullptr, nullptr, BZ, IN, Hp, IN);
}

// Round 13
// 318.166 us; speedup vs baseline: 1.1292x; 1.1292x over previous
//
#include <hip/hip_runtime.h>
#include <math.h>
#include <float.h>

// VQVAE forward, MI355X. Round 24: REVERT to the R17/R6 configuration --
// the session's measured best (323.5us). Ledger: every structural change
// since (B-packed-direct R19-R21, counted-vmcnt raw barriers R22, ADIRECT
// barrier-free R23) was net-negative or null: B-direct moved B's latency
// onto the lockstep critical path (G1 69.7 -> 73.9), ADIRECT dist exposed
// raw L2 latency (dist -> 89.5), and counted-vmcnt confirmed the 2-phase
// regime gate (G1 ~700-740 TF == m230/m233 structural ceiling) without
// escaping it. This file: 8-wave 128x128 blocks (G2 64x128), A+B both
// LDS-staged via glds with source-side bank swizzle, 2-phase staging,
// one __syncthreads per K-step, XCD-affine grid (blockIdx.x = row-block),
// LDS-staged coalesced epilogues, dist with full A+E glds staging,
// exact fp32 rescore of 12 candidates.

typedef __attribute__((ext_vector_type(8))) short short8;      // MFMA A/B frag
typedef __attribute__((ext_vector_type(4))) float floatx4;     // MFMA C/D frag
typedef __attribute__((ext_vector_type(4))) unsigned short ushort4v;
typedef __attribute__((ext_vector_type(8))) unsigned short ushort8v;

__device__ __forceinline__ unsigned short f2bf(float f) {
  union { float f; unsigned u; } v; v.f = f;
  unsigned u = v.u;
  return (unsigned short)((u + 0x7FFFu + ((u >> 16) & 1u)) >> 16);
}
__device__ __forceinline__ float bf2f(unsigned short s) {
  union { unsigned u; float f; } v; v.u = ((unsigned)s) << 16;
  return v.f;
}

__device__ __forceinline__ void glds16(const void* g, void* l) {
  __builtin_amdgcn_global_load_lds(
      (const __attribute__((address_space(1))) unsigned int*)g,
      (__attribute__((address_space(3))) unsigned int*)l, 16, 0, 0);
}

// bank-swizzle: 16B-chunk XOR within a row; uses row bits 0-3 only.
__device__ __forceinline__ int fswz(int r) { return (r ^ (r >> 2)) & 3; }

__device__ __forceinline__ unsigned packkey(float d, int c) {
  unsigned b = __float_as_uint(d);
  b = (b & 0x80000000u) ? ~b : (b | 0x80000000u);
  return (b & 0xFFFFF800u) | (unsigned)c;
}
__device__ __forceinline__ void ins3(unsigned k, unsigned& v1, unsigned& v2,
                                     unsigned& v3) {
  unsigned t1 = min(v1, k), c1 = max(v1, k);
  unsigned t2 = min(v2, c1), c2 = max(v2, c1);
  v1 = t1; v2 = t2; v3 = min(v3, c2);
}

// one fp32->hi/mid padded conversion element; Cp compile-time (shifts)
template <int Cp>
__device__ __forceinline__ void conv_one(
    const float* __restrict__ src, unsigned short* __restrict__ hi,
    unsigned short* __restrict__ mid, int R, int C, int b) {
  const int t = b * 256 + (int)threadIdx.x;
  const int r = t / Cp, c = t & (Cp - 1);
  float v = (r < R && c < C) ? src[(long)r * C + c] : 0.f;
  unsigned short h = f2bf(v);
  hi[t] = h;
  mid[t] = f2bf(v - bf2f(h));
}

// fused prep: regions (block counts): W1 2048 | W2 512 | W3 512 | W4 2048 |
// emb 2048 | enorm 512. Grid = 7680 blocks.
__global__ __launch_bounds__(256) void prep(
    const float* __restrict__ W1, unsigned short* __restrict__ w1h, unsigned short* __restrict__ w1m,
    const float* __restrict__ W2, unsigned short* __restrict__ w2h, unsigned short* __restrict__ w2m,
    const float* __restrict__ W3, unsigned short* __restrict__ w3h, unsigned short* __restrict__ w3m,
    const float* __restrict__ W4, unsigned short* __restrict__ w4h, unsigned short* __restrict__ w4m,
    const float* __restrict__ emb, unsigned short* __restrict__ eh, unsigned short* __restrict__ em,
    float* __restrict__ enorm) {
  int b = blockIdx.x;
  if (b < 2048) {                       // W1: 400x1024 -> 512x1024
    conv_one<1024>(W1, w1h, w1m, 400, 1024, b);
  } else if (b < 2560) {                // W2: 256x400 -> 256x512
    conv_one<512>(W2, w2h, w2m, 256, 400, b - 2048);
  } else if (b < 3072) {                // W3: 400x256 -> 512x256
    conv_one<256>(W3, w3h, w3m, 400, 256, b - 2560);
  } else if (b < 5120) {                // W4: 1024x400 -> 1024x512
    conv_one<512>(W4, w4h, w4m, 1024, 400, b - 3072);
  } else if (b < 7168) {                // emb: 2048x256 -> 2048x256
    conv_one<256>(emb, eh, em, 2048, 256, b - 5120);
  } else {                              // enorm: 4 rows/block, 1 wave/row
    const int gtid = (b - 7168) * 256 + (int)threadIdx.x;
    const int j = gtid >> 6;
    const int lane = threadIdx.x & 63;
    float4 v = *(const float4*)(emb + (long)j * 256 + (lane << 2));
    float s = v.x * v.x + v.y * v.y + v.z * v.z + v.w * v.w;
#pragma unroll
    for (int off = 1; off < 64; off <<= 1) s += __shfl_xor(s, off, 64);
    if (lane == 0) enorm[j] = s;
  }
}

#define BK 32

enum { EPI_NONE = 0, EPI_RELU = 1, EPI_SIGMOID = 2 };
// OMODE: 0 = fp32 out, 1 = hi/mid split out, 3 = hi-only bf16 out
// NPROD: 3 = ah*bh + ah*bm + am*bh (fp32-grade); 2 = ah*bh + ah*bm (A hi-only)
// Wave grid WM x WN; wave tile (TMW*16) x (TNW*16); BM = WM*TMW*16,
// BN = WN*TNW*16; THREADS = WM*WN*64.
// Grid: blockIdx.x = row-block (XCD-affine), blockIdx.y = col-block.

template <int EPI, bool INDIRECT, bool ASPLIT, int OMODE, int TMW, int TNW,
          int WM, int WN, int NPROD>
__global__ __launch_bounds__(WM * WN * 64, 4) void mfma_gemm(
    const float* __restrict__ Af, const unsigned short* __restrict__ Ahg,
    const unsigned short* __restrict__ Amg, const unsigned short* __restrict__ Bhi,
    const unsigned short* __restrict__ Bmid, const float* __restrict__ bias,
    float* __restrict__ Cf, unsigned short* __restrict__ Ohi,
    unsigned short* __restrict__ Omid, const int* __restrict__ aidx,
    int M, int N, int K, int Nreal) {
  constexpr int WAVES = WM * WN;
  constexpr int THREADS = WAVES * 64;
  constexpr int BM = WM * TMW * 16;
  constexpr int BN = WN * TNW * 16;
  constexpr int NSA = BM / 16;            // A 16-row staging slots
  constexpr int NSB = BN / 16;            // B 16-row staging slots
  constexpr int ASW = (NSA + WAVES - 1) / WAVES;
  constexpr int BSW = (NSB + WAVES - 1) / WAVES;
  constexpr int ACELL = (BM * BK) / (4 * THREADS);  // fp32-A staging cells
  constexpr int RPC = THREADS / 8;        // rows per fp32 staging cell

  // double-buffered staging; OutS epilogue staging aliases the whole union.
  constexpr int A_SH  = BM * BK;                                   // shorts
  constexpr int AM_SH = (NPROD == 3 || !ASPLIT) ? BM * BK : 0;     // shorts
  constexpr int B_SH  = BN * BK;                                   // shorts
  constexpr int STAGE_SH = A_SH + AM_SH + 2 * B_SH;                // one phase
  constexpr int OUT_SH = (OMODE == 0) ? 0 : BM * (BN + 8);
  constexpr int SMEM_SH = (2 * STAGE_SH > OUT_SH) ? 2 * STAGE_SH : OUT_SH;
  __shared__ __align__(16) unsigned short smem[SMEM_SH];
  unsigned short (*OutS)[BN + 8] = (unsigned short(*)[BN + 8])smem;

  const int tid = threadIdx.x, lane = tid & 63, wave = tid >> 6;
  const int wm = wave / WN, wn = wave % WN;
  const int row0 = blockIdx.x * BM, col0 = blockIdx.y * BN;
  // swizzled source K-chunk for glds staging (chunk = lane&3, row = lane>>2)
  const int kswz = (((lane & 3) ^ fswz(lane >> 2)) * 8);

  const unsigned short *aH[ASW], *aM2[ASW], *bH[BSW], *bM2[BSW];
  const float* aF[(ACELL > 0) ? ACELL : 1];
  if (ASPLIT) {
#pragma unroll
    for (int j = 0; j < ASW; j++) {
      const int slot = wave + j * WAVES;
      if (slot < NSA) {
        const int rl = slot * 16 + (lane >> 2);
        const long ar = INDIRECT ? (long)aidx[row0 + rl] : (long)(row0 + rl);
        aH[j] = Ahg + ar * K + kswz;
        if (NPROD == 3) aM2[j] = Amg + ar * K + kswz;
      }
    }
  } else {
#pragma unroll
    for (int i = 0; i < ACELL; i++)
      aF[i] = Af + (long)(row0 + i * RPC + (tid >> 3)) * K + (tid & 7) * 4;
  }
#pragma unroll
  for (int j = 0; j < BSW; j++) {
    const int slot = wave + j * WAVES;
    if (slot < NSB) {
      const int rl = slot * 16 + (lane >> 2);
      bH[j] = Bhi + (long)(col0 + rl) * K + kswz;
      bM2[j] = Bmid + (long)(col0 + rl) * K + kswz;
    }
  }

  // issue all async staging loads for K-step k0 into phase p
  auto stage_glds = [&](int p, int k0) {
    unsigned short* b = smem + p * STAGE_SH;
#pragma unroll
    for (int j = 0; j < BSW; j++) {
      const int slot = wave + j * WAVES;
      if (slot < NSB) {
        glds16(bH[j] + k0, b + A_SH + AM_SH + slot * 512);
        glds16(bM2[j] + k0, b + A_SH + AM_SH + B_SH + slot * 512);
      }
    }
    if (ASPLIT) {
#pragma unroll
      for (int j = 0; j < ASW; j++) {
        const int slot = wave + j * WAVES;
        if (slot < NSA) {
          glds16(aH[j] + k0, b + slot * 512);
          if (NPROD == 3) glds16(aM2[j] + k0, b + A_SH + slot * 512);
        }
      }
    }
  };
  // fp32-A path: convert regs -> hi/mid, write into phase p (swizzled cols)
  auto stage_awrite = [&](int p, const float4* areg) {
    unsigned short* b = smem + p * STAGE_SH;
#pragma unroll
    for (int i = 0; i < ACELL; i++) {
      const int r = i * RPC + (tid >> 3);
      const int c16 = (tid & 7) >> 1, lo = tid & 1;
      const int q4 = (((c16 ^ fswz(r)) << 1) | lo) * 4;
      ushort4v h, m;
      h.x = f2bf(areg[i].x); m.x = f2bf(areg[i].x - bf2f(h.x));
      h.y = f2bf(areg[i].y); m.y = f2bf(areg[i].y - bf2f(h.y));
      h.z = f2bf(areg[i].z); m.z = f2bf(areg[i].z - bf2f(h.z));
      h.w = f2bf(areg[i].w); m.w = f2bf(areg[i].w - bf2f(h.w));
      *(ushort4v*)(b + r * BK + q4) = h;
      *(ushort4v*)(b + A_SH + r * BK + q4) = m;
    }
  };

  floatx4 acc[TMW][TNW];
#pragma unroll
  for (int i = 0; i < TMW; i++)
#pragma unroll
    for (int j = 0; j < TNW; j++) acc[i][j] = (floatx4)0.f;

  // prologue: stage K-step 0 into phase 0
  if (!ASPLIT) {
    float4 a0[(ACELL > 0) ? ACELL : 1];
#pragma unroll
    for (int i = 0; i < ACELL; i++) a0[i] = *(const float4*)(aF[i]);
    stage_awrite(0, a0);
  }
  stage_glds(0, 0);
  __syncthreads();

  int p = 0;
  for (int k0 = 0; k0 < K; k0 += BK) {
    const bool more = (k0 + BK) < K;
    float4 an[(ACELL > 0) ? ACELL : 1];
    if (more) {
      if (!ASPLIT) {
#pragma unroll
        for (int i = 0; i < ACELL; i++) an[i] = *(const float4*)(aF[i] + k0 + BK);
      }
      stage_glds(p ^ 1, k0 + BK);
    }
    // compute from phase p (reads apply the same chunk swizzle)
    {
      const unsigned short* b = smem + p * STAGE_SH;
      short8 ah[TMW], am[TMW];
#pragma unroll
      for (int tm = 0; tm < TMW; tm++) {
        const int rr = wm * (TMW * 16) + tm * 16 + (lane & 15);
        const int kk = (((lane >> 4) ^ fswz(rr)) * 8);
        ah[tm] = *(const short8*)(b + rr * BK + kk);
        if (NPROD == 3) am[tm] = *(const short8*)(b + A_SH + rr * BK + kk);
      }
#pragma unroll
      for (int tn = 0; tn < TNW; tn++) {
        const int rr = wn * (TNW * 16) + tn * 16 + (lane & 15);
        const int kk = (((lane >> 4) ^ fswz(rr)) * 8);
        short8 bh = *(const short8*)(b + A_SH + AM_SH + rr * BK + kk);
        short8 bm = *(const short8*)(b + A_SH + AM_SH + B_SH + rr * BK + kk);
#pragma unroll
        for (int tm = 0; tm < TMW; tm++) {
          acc[tm][tn] = __builtin_amdgcn_mfma_f32_16x16x32_bf16(ah[tm], bh, acc[tm][tn], 0, 0, 0);
          acc[tm][tn] = __builtin_amdgcn_mfma_f32_16x16x32_bf16(ah[tm], bm, acc[tm][tn], 0, 0, 0);
          if (NPROD == 3)
            acc[tm][tn] = __builtin_amdgcn_mfma_f32_16x16x32_bf16(am[tm], bh, acc[tm][tn], 0, 0, 0);
        }
      }
    }
    if (more && !ASPLIT) stage_awrite(p ^ 1, an);
    __syncthreads();  // next-phase staging drained; this-phase reads done
    p ^= 1;
  }

  // C/D layout: col = lane&15, row = (lane>>4)*4 + reg
  const int qd = lane >> 4, ln = lane & 15;
  if (OMODE == 0) {
#pragma unroll
    for (int tn = 0; tn < TNW; tn++) {
      const int c = col0 + wn * (TNW * 16) + tn * 16 + ln;
      const float bb = (c < Nreal) ? bias[c] : 0.f;
#pragma unroll
      for (int tm = 0; tm < TMW; tm++) {
#pragma unroll
        for (int reg = 0; reg < 4; reg++) {
          const int r = row0 + wm * (TMW * 16) + tm * 16 + qd * 4 + reg;
          float v = acc[tm][tn][reg] + bb;
          if (EPI == EPI_RELU) v = fmaxf(v, 0.f);
          if (EPI == EPI_SIGMOID) v = 1.f / (1.f + __expf(-v));
          Cf[(long)r * N + c] = v;
        }
      }
    }
  } else {
    // staged bf16 epilogue: full-cache-line coalesced writes. (The K-loop's
    // final barrier already ordered all staging reads before OutS aliasing.)
    float bbv[TNW];
#pragma unroll
    for (int tn = 0; tn < TNW; tn++) {
      const int c = col0 + wn * (TNW * 16) + tn * 16 + ln;
      bbv[tn] = (c < Nreal) ? bias[c] : 0.f;
    }
    constexpr int CPR = BN / 8;                    // 16B chunks per row
    constexpr int NCH = (BM * BN) / (THREADS * 8); // chunks per thread
    // pass 1: hi
#pragma unroll
    for (int tn = 0; tn < TNW; tn++) {
      const int cl = wn * (TNW * 16) + tn * 16 + ln;
#pragma unroll
      for (int tm = 0; tm < TMW; tm++) {
#pragma unroll
        for (int reg = 0; reg < 4; reg++) {
          const int rl = wm * (TMW * 16) + tm * 16 + qd * 4 + reg;
          float v = acc[tm][tn][reg] + bbv[tn];
          if (EPI == EPI_RELU) v = fmaxf(v, 0.f);
          if (EPI == EPI_SIGMOID) v = 1.f / (1.f + __expf(-v));
          OutS[rl][cl] = f2bf(v);
        }
      }
    }
    __syncthreads();
#pragma unroll
    for (int i = 0; i < NCH; i++) {
      const int g = tid + THREADS * i;
      const int row = g / CPR, cc = g % CPR;
      ushort8v val = *(const ushort8v*)&OutS[row][cc * 8];
      *(ushort8v*)(Ohi + (long)(row0 + row) * N + col0 + cc * 8) = val;
    }
    if (OMODE == 1) {
      __syncthreads();
      // pass 2: mid
#pragma unroll
      for (int tn = 0; tn < TNW; tn++) {
        const int cl = wn * (TNW * 16) + tn * 16 + ln;
#pragma unroll
        for (int tm = 0; tm < TMW; tm++) {
#pragma unroll
          for (int reg = 0; reg < 4; reg++) {
            const int rl = wm * (TMW * 16) + tm * 16 + qd * 4 + reg;
            float v = acc[tm][tn][reg] + bbv[tn];
            if (EPI == EPI_RELU) v = fmaxf(v, 0.f);
            if (EPI == EPI_SIGMOID) v = 1.f / (1.f + __expf(-v));
            unsigned short h = f2bf(v);
            OutS[rl][cl] = f2bf(v - bf2f(h));
          }
        }
      }
      __syncthreads();
#pragma unroll
      for (int i = 0; i < NCH; i++) {
        const int g = tid + THREADS * i;
        const int row = g / CPR, cc = g % CPR;
        ushort8v val = *(const ushort8v*)&OutS[row][cc * 8];
        *(ushort8v*)(Omid + (long)(row0 + row) * N + col0 + cc * 8) = val;
      }
    }
  }
}

// dist candidates: grid (M/128 rows, 4 groups); block sweeps 512 cols in 4
// chunks of 128, flattened to 32 pipelined (chunk,k) iterations (2-phase
// double-buffered staging, one barrier/iter). Grid-x = row-block => XCD =
// rowblock%8: codebook strips stay L2-resident per XCD. Branchless packed-key
// top-3, one cross-lane merge. Reduce scratch aliases staging LDS.
__global__ __launch_bounds__(256, 2) void dist_topk(
    const unsigned short* __restrict__ Zh, const unsigned short* __restrict__ Zm,
    const unsigned short* __restrict__ Eh, const unsigned short* __restrict__ Em,
    const float* __restrict__ enorm, int* __restrict__ pidx, int M) {
  const int K = 256;
  constexpr int STG = 4 * 128 * BK;  // shorts per phase (Ah|Am|Bh|Bm)
  __shared__ __align__(16) unsigned short smem[2 * STG];
  unsigned* rs = (unsigned*)smem;    // [3][2][128] reduce scratch (end only)

  const int tid = threadIdx.x, lane = tid & 63, wave = tid >> 6;
  const int wm = wave >> 1, wn = wave & 1;
  const int row0 = blockIdx.x * 128;
  const int col_base = blockIdx.y * 512;
  const int kswz = (((lane & 3) ^ fswz(lane >> 2)) * 8);

  const unsigned short *aH[2], *aM2[2];
  int rlj[2];
#pragma unroll
  for (int j = 0; j < 2; j++) {
    rlj[j] = (wave * 2 + j) * 16 + (lane >> 2);
    aH[j] = Zh + (long)(row0 + rlj[j]) * K + kswz;
    aM2[j] = Zm + (long)(row0 + rlj[j]) * K + kswz;
  }

  auto stage = [&](int p, int it) {
    const int ch = it >> 3, k0 = (it & 7) * BK;
    const int c0 = col_base + ch * 128;
    unsigned short* b = smem + p * STG;
#pragma unroll
    for (int j = 0; j < 2; j++) {
      const int slot = wave * 2 + j;
      glds16(aH[j] + k0, b + slot * 512);
      glds16(aM2[j] + k0, b + 4096 + slot * 512);
      glds16(Eh + (long)(c0 + rlj[j]) * K + kswz + k0, b + 8192 + slot * 512);
      glds16(Em + (long)(c0 + rlj[j]) * K + kswz + k0, b + 12288 + slot * 512);
    }
  };

  unsigned k1[16], k2[16], k3[16];
#pragma unroll
  for (int s = 0; s < 16; s++) { k1[s] = 0xFFFFFFFFu; k2[s] = 0xFFFFFFFFu; k3[s] = 0xFFFFFFFFu; }

  floatx4 acc[4][4];
  stage(0, 0);
  __syncthreads();
  int p = 0;
  for (int it = 0; it < 32; it++) {
    if ((it & 7) == 0) {
#pragma unroll
      for (int i = 0; i < 4; i++)
#pragma unroll
        for (int j = 0; j < 4; j++) acc[i][j] = (floatx4)0.f;
    }
    if (it + 1 < 32) stage(p ^ 1, it + 1);
    {
      const unsigned short* b = smem + p * STG;
      short8 ah[4], am[4];
#pragma unroll
      for (int tm = 0; tm < 4; tm++) {
        const int rr = wm * 64 + tm * 16 + (lane & 15);
        const int kk = (((lane >> 4) ^ fswz(rr)) * 8);
        ah[tm] = *(const short8*)(b + rr * BK + kk);
        am[tm] = *(const short8*)(b + 4096 + rr * BK + kk);
      }
#pragma unroll
      for (int tn = 0; tn < 4; tn++) {
        const int rr = wn * 64 + tn * 16 + (lane & 15);
        const int kk = (((lane >> 4) ^ fswz(rr)) * 8);
        short8 bh = *(const short8*)(b + 8192 + rr * BK + kk);
        short8 bm = *(const short8*)(b + 12288 + rr * BK + kk);
#pragma unroll
        for (int tm = 0; tm < 4; tm++) {
          acc[tm][tn] = __builtin_amdgcn_mfma_f32_16x16x32_bf16(ah[tm], bh, acc[tm][tn], 0, 0, 0);
          acc[tm][tn] = __builtin_amdgcn_mfma_f32_16x16x32_bf16(ah[tm], bm, acc[tm][tn], 0, 0, 0);
          acc[tm][tn] = __builtin_amdgcn_mfma_f32_16x16x32_bf16(am[tm], bh, acc[tm][tn], 0, 0, 0);
        }
      }
    }
    if ((it & 7) == 7) {  // chunk epilogue: fold into top-3
      const int c0 = col_base + (it >> 3) * 128;
#pragma unroll
      for (int tn = 0; tn < 4; tn++) {
        const int c = c0 + wn * 64 + tn * 16 + (lane & 15);
        const float en = enorm[c];
#pragma unroll
        for (int tm = 0; tm < 4; tm++)
#pragma unroll
          for (int reg = 0; reg < 4; reg++) {
            float d = en - 2.f * acc[tm][tn][reg];
            ins3(packkey(d, c), k1[tm * 4 + reg], k2[tm * 4 + reg], k3[tm * 4 + reg]);
          }
      }
    }
    __syncthreads();
    p ^= 1;
  }

#pragma unroll
  for (int s = 0; s < 16; s++) {
#pragma unroll
    for (int off = 1; off < 16; off <<= 1) {
      unsigned o1 = __shfl_xor(k1[s], off, 64);
      unsigned o2 = __shfl_xor(k2[s], off, 64);
      unsigned o3 = __shfl_xor(k3[s], off, 64);
      ins3(o1, k1[s], k2[s], k3[s]);
      ins3(o2, k1[s], k2[s], k3[s]);
      ins3(o3, k1[s], k2[s], k3[s]);
    }
  }
  if ((lane & 15) == 0) {
#pragma unroll
    for (int s = 0; s < 16; s++) {
      int rl = wm * 64 + (s >> 2) * 16 + (lane >> 4) * 4 + (s & 3);
      rs[0 + wn * 128 + rl] = k1[s];
      rs[256 + wn * 128 + rl] = k2[s];
      rs[512 + wn * 128 + rl] = k3[s];
    }
  }
  __syncthreads();
  if (tid < 128) {
    unsigned v1 = rs[0 + tid], v2 = rs[256 + tid], v3 = rs[512 + tid];
    ins3(rs[0 + 128 + tid], v1, v2, v3);
    ins3(rs[256 + 128 + tid], v1, v2, v3);
    ins3(rs[512 + 128 + tid], v1, v2, v3);
    const long base = ((long)blockIdx.y * M + (row0 + tid)) * 4;
    pidx[base + 0] = (int)(v1 & 0x7FFu);
    pidx[base + 1] = (int)(v2 & 0x7FFu);
    pidx[base + 2] = (int)(v3 & 0x7FFu);
  }
}

// exact fp32 rescore of 12 candidates/row; z = hi + mid (bit-identical to the
// value the dist kernel scored). One wave per row.
__global__ __launch_bounds__(256) void rescore(
    const unsigned short* __restrict__ zh, const unsigned short* __restrict__ zm,
    const float* __restrict__ emb, const float* __restrict__ enorm,
    const int* __restrict__ pidx, int* __restrict__ idx, int M) {
  const int wave = threadIdx.x >> 6, lane = threadIdx.x & 63;
  const int r = blockIdx.x * 4 + wave;
  ushort4v hz = *(const ushort4v*)(zh + (long)r * 256 + lane * 4);
  ushort4v mz = *(const ushort4v*)(zm + (long)r * 256 + lane * 4);
  float4 zv;
  zv.x = bf2f(hz.x) + bf2f(mz.x);
  zv.y = bf2f(hz.y) + bf2f(mz.y);
  zv.z = bf2f(hz.z) + bf2f(mz.z);
  zv.w = bf2f(hz.w) + bf2f(mz.w);
  float best = FLT_MAX;
  int bi = 0x7fffffff;
  for (int g = 0; g < 4; g++) {
#pragma unroll
    for (int s = 0; s < 3; s++) {
      const int j = pidx[((long)g * M + r) * 4 + s];
      float4 ev = *(const float4*)(emb + (long)j * 256 + lane * 4);
      float t = zv.x * ev.x + zv.y * ev.y + zv.z * ev.z + zv.w * ev.w;
#pragma unroll
      for (int off = 1; off < 64; off <<= 1) t += __shfl_xor(t, off, 64);
      const float d = enorm[j] - 2.f * t;
      if (d < best || (d == best && j < bi)) { best = d; bi = j; }
    }
  }
  if (lane == 0) idx[r] = bi;
}

extern "C" void kernel_launch(void* const* d_in, const int* in_sizes, int n_in,
                              void* d_out, int out_size, void* d_ws, size_t ws_size,
                              hipStream_t stream) {
  const float* x   = (const float*)d_in[0];
  const float* W1  = (const float*)d_in[1];
  const float* b1  = (const float*)d_in[2];
  const float* W2  = (const float*)d_in[3];
  const float* b2  = (const float*)d_in[4];
  const float* W3  = (const float*)d_in[5];
  const float* b3  = (const float*)d_in[6];
  const float* W4  = (const float*)d_in[7];
  const float* b4  = (const float*)d_in[8];
  const float* emb = (const float*)d_in[9];
  float* out = (float*)d_out;

  const int BZ = 16384, IN = 1024, H = 400, Hp = 512, D = 256;

  char* ws = (char*)d_ws;
  size_t off = 0;
  auto alloc = [&](size_t bytes) {
    void* p = ws + off;
    off += (bytes + 255) & ~(size_t)255;
    return p;
  };
  unsigned short* w1h = (unsigned short*)alloc((size_t)Hp * IN * 2);
  unsigned short* w1m = (unsigned short*)alloc((size_t)Hp * IN * 2);
  unsigned short* w2h = (unsigned short*)alloc((size_t)D * Hp * 2);
  unsigned short* w2m = (unsigned short*)alloc((size_t)D * Hp * 2);
  unsigned short* w3h = (unsigned short*)alloc((size_t)Hp * D * 2);
  unsigned short* w3m = (unsigned short*)alloc((size_t)Hp * D * 2);
  unsigned short* w4h = (unsigned short*)alloc((size_t)IN * Hp * 2);
  unsigned short* w4m = (unsigned short*)alloc((size_t)IN * Hp * 2);
  unsigned short* eh  = (unsigned short*)alloc((size_t)2048 * D * 2);
  unsigned short* em  = (unsigned short*)alloc((size_t)2048 * D * 2);
  float* enorm = (float*)alloc((size_t)2048 * 4);
  unsigned short* h1h = (unsigned short*)alloc((size_t)BZ * Hp * 2);  // 16MB
  unsigned short* h1m = (unsigned short*)alloc((size_t)BZ * Hp * 2);  // 16MB
  unsigned short* zh  = (unsigned short*)alloc((size_t)BZ * D * 2);   // 8MB
  unsigned short* zm  = (unsigned short*)alloc((size_t)BZ * D * 2);   // 8MB
  // aliases (lifetimes disjoint on the sequential stream):
  int* pidx = (int*)h1h;                       // h1 dead after GEMM2 (1MB used)
  int* idx  = ((int*)h1h) + (size_t)4 * BZ * 4;
  unsigned short* h3h = h1m;                   // h1m dead after GEMM2 (16MB)

  // fused prep: all weight/codebook conversions + emb norms in one dispatch
  prep<<<dim3(7680), dim3(256), 0, stream>>>(
      W1, w1h, w1m, W2, w2h, w2m, W3, w3h, w3m, W4, w4h, w4m, emb, eh, em, enorm);

  // h1 = relu(x @ W1^T + b1) -> hi/mid [BZ][512]  (bf16x3, 128x128, 8 waves)
  mfma_gemm<EPI_RELU, false, false, 1, 4, 2, 2, 4, 3><<<dim3(BZ / 128, Hp / 128), dim3(512), 0, stream>>>(
      x, nullptr, nullptr, w1h, w1m, b1, nullptr, h1h, h1m, nullptr, BZ, Hp, IN, H);
  // z = h1 @ W2^T + b2 -> hi/mid [BZ][256]   (bf16x3, 64x128, 8 waves)
  mfma_gemm<EPI_NONE, false, true, 1, 2, 2, 2, 4, 3><<<dim3(BZ / 64, D / 128), dim3(512), 0, stream>>>(
      nullptr, h1h, h1m, w2h, w2m, b2, nullptr, zh, zm, nullptr, BZ, D, Hp, D);
  // dist candidates: top-3 per 512-col group (XCD-affine grid), bf16x3
  dist_topk<<<dim3(BZ / 128, 4), dim3(256), 0, stream>>>(zh, zm, eh, em, enorm, pidx, BZ);
  // exact fp32 rescore of 12 -> idx
  rescore<<<dim3(BZ / 4), dim3(256), 0, stream>>>(zh, zm, emb, enorm, pidx, idx, BZ);
  // h3 = relu(emb[idx] @ W3^T + b3) -> bf16 hi only (bf16x2, 128x128, 8 waves)
  mfma_gemm<EPI_RELU, true, true, 3, 4, 2, 2, 4, 2><<<dim3(BZ / 128, Hp / 128), dim3(512), 0, stream>>>(
      nullptr, eh, nullptr, w3h, w3m, b3, nullptr, h3h, nullptr, idx, BZ, Hp, D, H);
  // out = sigmoid(h3 @ W4^T + b4) -> fp32 [BZ][1024] (bf16x2, 128x128, 8 waves)
  mfma_gemm<EPI_SIGMOID, false, true, 0, 4, 2, 2, 4, 2><<<dim3(BZ / 128, IN / 128), dim3(512), 0, stream>>>(
      nullptr, h3h, nullptr, w4h, w4m, b4, out, nullptr, nullptr, nullptr, BZ, IN, Hp, IN);
}